// Round 2
// baseline (370.536 us; speedup 1.0000x reference)
//
#include <hip/hip_runtime.h>
#include <hip/hip_bf16.h>
#include <stdint.h>

typedef __bf16 bf16_t;
typedef __bf16 bf16x8 __attribute__((ext_vector_type(8)));
typedef float  f32x4  __attribute__((ext_vector_type(4)));

__device__ __forceinline__ void gload16(const void* gp, void* lp) {
  __builtin_amdgcn_global_load_lds(
      (const __attribute__((address_space(1))) void*)(uintptr_t)gp,
      (__attribute__((address_space(3))) void*)(uintptr_t)lp,
      16, 0, 0);
}

__device__ __forceinline__ f32x4 mfma16(bf16x8 a, bf16x8 b, f32x4 c) {
  return __builtin_amdgcn_mfma_f32_16x16x32_bf16(a, b, c, 0, 0, 0);
}

// ---------------- fp32 -> bf16 cast (memory-bound, vectorized) ----------------
__global__ __launch_bounds__(256) void cast_f32_to_bf16(const float* __restrict__ in,
                                                        bf16_t* __restrict__ out, int n8) {
  int i = blockIdx.x * 256 + threadIdx.x;
  int stride = gridDim.x * 256;
  for (; i < n8; i += stride) {
    const f32x4* p = (const f32x4*)in + (size_t)i * 2;
    f32x4 a = p[0], b = p[1];
    bf16x8 o;
    o[0] = (bf16_t)a[0]; o[1] = (bf16_t)a[1]; o[2] = (bf16_t)a[2]; o[3] = (bf16_t)a[3];
    o[4] = (bf16_t)b[0]; o[5] = (bf16_t)b[1]; o[6] = (bf16_t)b[2]; o[7] = (bf16_t)b[3];
    ((bf16x8*)out)[i] = o;
  }
}

// ---------------- bf16 GEMM, C[m][n] = sum_k A[m][k]*B[n][k]  (m97 structure) ----------------
template<bool OUT_BF16>
__global__ __launch_bounds__(256, 2) void gemm_bt(const bf16_t* __restrict__ A,
                                                  const bf16_t* __restrict__ B,
                                                  void* __restrict__ Cout,
                                                  int M, int N, int K) {
  __shared__ __align__(16) bf16_t As[128 * 32];
  __shared__ __align__(16) bf16_t Bs[128 * 32];
  const int t = threadIdx.x;
  const int wid = t >> 6;
  const int l = t & 63;
  const int l15 = l & 15, l4 = l >> 4;
  const int wr = wid >> 1, wc = wid & 1;
  const long m0 = (long)blockIdx.x * 128;
  const long n0 = (long)blockIdx.y * 128;
  f32x4 acc[4][4] = {};
  for (int k0 = 0; k0 < K; k0 += 32) {
    #pragma unroll
    for (int it = 0; it < 2; ++it) {
      int idx = it * 256 + t;
      int row = idx >> 2, ch = idx & 3;   // 4x16B chunks per 64B row
      gload16(A + (m0 + row) * K + k0 + ch * 8, As + (size_t)(it * 256 + wid * 64) * 8);
      gload16(B + (n0 + row) * K + k0 + ch * 8, Bs + (size_t)(it * 256 + wid * 64) * 8);
    }
    __syncthreads();
    bf16x8 af[4], bfr[4];
    #pragma unroll
    for (int mf = 0; mf < 4; ++mf)
      af[mf] = *(const bf16x8*)(As + (wr * 64 + mf * 16 + l15) * 32 + l4 * 8);
    #pragma unroll
    for (int nf = 0; nf < 4; ++nf)
      bfr[nf] = *(const bf16x8*)(Bs + (wc * 64 + nf * 16 + l15) * 32 + l4 * 8);
    #pragma unroll
    for (int mf = 0; mf < 4; ++mf)
      #pragma unroll
      for (int nf = 0; nf < 4; ++nf)
        acc[mf][nf] = mfma16(af[mf], bfr[nf], acc[mf][nf]);
    __syncthreads();
  }
  // C/D layout: col = lane&15, row = (lane>>4)*4 + i   (m89-verified)
  #pragma unroll
  for (int mf = 0; mf < 4; ++mf)
    #pragma unroll
    for (int nf = 0; nf < 4; ++nf)
      #pragma unroll
      for (int i = 0; i < 4; ++i) {
        long r = m0 + wr * 64 + mf * 16 + l4 * 4 + i;
        long c = n0 + wc * 64 + nf * 16 + l15;
        if (OUT_BF16) ((bf16_t*)Cout)[r * N + c] = (bf16_t)acc[mf][nf][i];
        else          ((float*)Cout)[r * N + c] = acc[mf][nf][i];
      }
}

// ---------------- RoPE (rot_dim=32) + q-scale, in-place on qkv[4096][6144] ----------------
__global__ __launch_bounds__(256) void rope_scale(bf16_t* __restrict__ qkv) {
  int t = blockIdx.x * 256 + threadIdx.x;    // [0, 4096*256)
  int m = t >> 8;
  int h = (t >> 4) & 15;
  int j = t & 15;
  int n = m & 2047;
  const float L2_10000_D16 = 0.8304820237218406f;  // log2(10000)/16
  float inv = exp2f(-(float)j * L2_10000_D16);     // 10000^(-j/16)
  float ang = (float)n * inv;
  float s, c;
  sincosf(ang, &s, &c);
  const float scale = 0.08838834764831845f;        // 128^-0.5
  bf16_t* qp = qkv + (long)m * 6144 + h * 128;
  float a = (float)qp[j], b = (float)qp[j + 16];
  qp[j]      = (bf16_t)((a * c - b * s) * scale);
  qp[j + 16] = (bf16_t)((b * c + a * s) * scale);
  #pragma unroll
  for (int u = 0; u < 6; ++u) {
    int d = 32 + j + u * 16;
    qp[d] = (bf16_t)((float)qp[d] * scale);
  }
  bf16_t* kp = qp + 2048;
  a = (float)kp[j]; b = (float)kp[j + 16];
  kp[j]      = (bf16_t)(a * c - b * s);
  kp[j + 16] = (bf16_t)(b * c + a * s);
}

// ---------------- causal flash attention ----------------
// grid (qt=16, bh=32), 256 thr (4 waves). Wave w owns q rows qt*128+w*32..+31.
// K: LDS [64][128] XOR-swizzled (16B chunk ^= row&7), staged via pre-swizzled global src.
// V: per-lane global row loads -> regs -> transposed into padded Vt[128][136]:
//    Vt[d][kv], row stride 136 el (16B aligned; fragment reads bank-balanced).
__global__ __launch_bounds__(256, 2) void attn_causal(const bf16_t* __restrict__ qkv,
                                                      bf16_t* __restrict__ ao) {
  const int qt = blockIdx.x;
  const int bh = blockIdx.y;
  const int b = bh >> 4, h = bh & 15;
  const int t = threadIdx.x;
  const int wid = t >> 6, l = t & 63;
  const int l15 = l & 15, l4 = l >> 4;
  __shared__ __align__(16) bf16_t Ks[64 * 128];
  __shared__ __align__(16) bf16_t Vt[128 * 136];
  __shared__ __align__(16) bf16_t Ps[4][32 * 64];
  const bf16_t* base = qkv + (long)b * 2048 * 6144 + h * 128;
  const int q0w = qt * 128 + wid * 32;
  // Q fragments in registers (A-layout: row=l&15, k=(l>>4)*8+j)
  bf16x8 qf[2][4];
  #pragma unroll
  for (int mb = 0; mb < 2; ++mb)
    #pragma unroll
    for (int ks = 0; ks < 4; ++ks)
      qf[mb][ks] = *(const bf16x8*)(base + (long)(q0w + mb * 16 + l15) * 6144 + ks * 32 + l4 * 8);
  f32x4 o[2][8] = {};
  float mrun[2][4], lrun[2][4];
  #pragma unroll
  for (int mb = 0; mb < 2; ++mb)
    #pragma unroll
    for (int i = 0; i < 4; ++i) { mrun[mb][i] = -3.0e38f; lrun[mb][i] = 0.f; }

  bf16_t* pbuf = Ps[wid];
  const int ntiles = 2 * qt + 2;
  for (int tile = 0; tile < ntiles; ++tile) {
    const int kv0 = tile * 64;
    // V: lane l loads 4x16B of global row (kv0+l); transpose into Vt[d][kv=l]
    bf16x8 vreg[4];
    const bf16_t* vsr = base + 4096 + (long)(kv0 + l) * 6144;
    #pragma unroll
    for (int it = 0; it < 4; ++it)
      vreg[it] = *(const bf16x8*)(vsr + (it * 4 + wid) * 8);
    // K: global_load_lds, pre-swizzled source column
    #pragma unroll
    for (int it = 0; it < 4; ++it) {
      int s = it * 256 + t;                    // 16B-chunk id, 0..1023
      int krow = s >> 4, kc = s & 15;
      int ksc = kc ^ (krow & 7);               // pre-swizzled source column
      gload16(base + 2048 + (long)(kv0 + krow) * 6144 + ksc * 8,
              Ks + (size_t)(it * 256 + wid * 64) * 8);
    }
    #pragma unroll
    for (int it = 0; it < 4; ++it) {
      int c = it * 4 + wid;                    // d-chunk 0..15
      #pragma unroll
      for (int i = 0; i < 8; ++i)
        Vt[(c * 8 + i) * 136 + l] = vreg[it][i];
    }
    __syncthreads();
    if (kv0 <= q0w + 31) {
      // S = Q K^T (D: row=q-local, col=kv-local)
      f32x4 sa[2][4] = {};
      #pragma unroll
      for (int ks = 0; ks < 4; ++ks) {
        #pragma unroll
        for (int nb = 0; nb < 4; ++nb) {
          int row = nb * 16 + l15;
          int cs = (ks * 4 + l4) ^ (row & 7);
          bf16x8 kf = *(const bf16x8*)(Ks + row * 128 + cs * 8);
          sa[0][nb] = mfma16(qf[0][ks], kf, sa[0][nb]);
          sa[1][nb] = mfma16(qf[1][ks], kf, sa[1][nb]);
        }
      }
      // online softmax (fp32); row stats via shfl_xor over the 16-lane col group
      #pragma unroll
      for (int mb = 0; mb < 2; ++mb) {
        #pragma unroll
        for (int i = 0; i < 4; ++i) {
          const int qrow = q0w + mb * 16 + l4 * 4 + i;
          float mt = -3.0e38f;
          #pragma unroll
          for (int nb = 0; nb < 4; ++nb) {
            int kvg = kv0 + nb * 16 + l15;
            float sv = sa[mb][nb][i];
            sv = (kvg <= qrow) ? sv : -3.0e38f;
            sa[mb][nb][i] = sv;
            mt = fmaxf(mt, sv);
          }
          mt = fmaxf(mt, __shfl_xor(mt, 1));
          mt = fmaxf(mt, __shfl_xor(mt, 2));
          mt = fmaxf(mt, __shfl_xor(mt, 4));
          mt = fmaxf(mt, __shfl_xor(mt, 8));
          const float mold = mrun[mb][i];
          const float mnew = fmaxf(mold, mt);
          const float corr = __expf(mold - mnew);
          float ps = 0.f;
          #pragma unroll
          for (int nb = 0; nb < 4; ++nb) {
            float p = __expf(sa[mb][nb][i] - mnew);
            sa[mb][nb][i] = p;
            ps += p;
          }
          ps += __shfl_xor(ps, 1);
          ps += __shfl_xor(ps, 2);
          ps += __shfl_xor(ps, 4);
          ps += __shfl_xor(ps, 8);
          mrun[mb][i] = mnew;
          lrun[mb][i] = lrun[mb][i] * corr + ps;
          #pragma unroll
          for (int nf = 0; nf < 8; ++nf) o[mb][nf][i] *= corr;
        }
      }
      // P -> per-wave LDS (bf16, XOR-swizzled 8-el chunks of [32][64])
      #pragma unroll
      for (int mb = 0; mb < 2; ++mb)
        #pragma unroll
        for (int nb = 0; nb < 4; ++nb)
          #pragma unroll
          for (int i = 0; i < 4; ++i) {
            int prow = mb * 16 + l4 * 4 + i;
            int pcol = nb * 16 + l15;
            int cw = (pcol >> 3) ^ (prow & 7);
            pbuf[prow * 64 + cw * 8 + (pcol & 7)] = (bf16_t)sa[mb][nb][i];
          }
      // O += P V   (A = P from LDS; B = V from transposed Vt, plain b128 reads)
      #pragma unroll
      for (int ks2 = 0; ks2 < 2; ++ks2) {
        bf16x8 pf0, pf1;
        {
          int cs0 = (ks2 * 4 + l4) ^ (l15 & 7);
          pf0 = *(const bf16x8*)(pbuf + l15 * 64 + cs0 * 8);
          int prow1 = 16 + l15;
          int cs1 = (ks2 * 4 + l4) ^ (prow1 & 7);
          pf1 = *(const bf16x8*)(pbuf + prow1 * 64 + cs1 * 8);
        }
        #pragma unroll
        for (int nf = 0; nf < 8; ++nf) {
          bf16x8 vf = *(const bf16x8*)(Vt + (nf * 16 + l15) * 136 + ks2 * 32 + l4 * 8);
          o[0][nf] = mfma16(pf0, vf, o[0][nf]);
          o[1][nf] = mfma16(pf1, vf, o[1][nf]);
        }
      }
    }
    __syncthreads();
  }
  // epilogue: O /= l, write bf16 to ao[b][n][h*128+d]
  bf16_t* aob = ao + (long)b * 2048 * 2048 + h * 128;
  #pragma unroll
  for (int mb = 0; mb < 2; ++mb)
    #pragma unroll
    for (int i = 0; i < 4; ++i) {
      long qrow = q0w + mb * 16 + l4 * 4 + i;
      float inv = 1.f / lrun[mb][i];
      #pragma unroll
      for (int nf = 0; nf < 8; ++nf)
        aob[qrow * 2048 + nf * 16 + l15] = (bf16_t)(o[mb][nf][i] * inv);
    }
}

// ---------------- launch ----------------
extern "C" void kernel_launch(void* const* d_in, const int* in_sizes, int n_in,
                              void* d_out, int out_size, void* d_ws, size_t ws_size,
                              hipStream_t stream) {
  const float* x     = (const float*)d_in[0];
  const float* w_qkv = (const float*)d_in[1];
  const float* w_out = (const float*)d_in[2];
  // d_in[3] (g) is unused by the reference.
  char* ws = (char*)d_ws;
  bf16_t* xb    = (bf16_t*)(ws + 0L);           // 16 MiB  (4096x2048)
  bf16_t* wqkvb = (bf16_t*)(ws + 16777216L);    // 24 MiB  (6144x2048)
  bf16_t* woutb = (bf16_t*)(ws + 41943040L);    //  8 MiB  (2048x2048)
  bf16_t* qkv   = (bf16_t*)(ws + 50331648L);    // 48 MiB  (4096x6144)
  bf16_t* ao    = (bf16_t*)(ws + 100663296L);   // 16 MiB  (4096x2048) -> end 112 MiB

  cast_f32_to_bf16<<<2048, 256, 0, stream>>>(x, xb, 1048576);
  cast_f32_to_bf16<<<2048, 256, 0, stream>>>(w_qkv, wqkvb, 1572864);
  cast_f32_to_bf16<<<1024, 256, 0, stream>>>(w_out, woutb, 524288);
  // qkv[m][f] = sum_c x[m][c] * w_qkv[f][c]
  gemm_bt<true ><<<dim3(32, 48), 256, 0, stream>>>(xb, wqkvb, (void*)qkv, 4096, 6144, 2048);
  rope_scale<<<4096, 256, 0, stream>>>(qkv);
  attn_causal<<<dim3(16, 32), 256, 0, stream>>>(qkv, ao);
  // out[m][c] = sum_f ao[m][f] * w_out[c][f]
  gemm_bt<false><<<dim3(32, 16), 256, 0, stream>>>(ao, woutb, d_out, 4096, 2048, 2048);
}